// Round 14
// baseline (2034.847 us; speedup 1.0000x reference)
//
#include <hip/hip_runtime.h>
#include <stdint.h>

#define N_TOK 8192
#define DIM   2048
#define NEXP  16
#define HID   1408
#define SHID  2816
#define KTOP  4
#define TILEMAX 272    // 128-row tiles: sum ceil(cnt/128) <= 272 = 8*34
#define TILEMAX2 144   // 256-row tiles: sum ceil(cnt/256) <= 144 = 8*18

typedef __attribute__((ext_vector_type(8))) short bf16x8;
typedef __attribute__((ext_vector_type(4))) float f32x4;

#define MFMA16(a,b,c) __builtin_amdgcn_mfma_f32_16x16x32_bf16((a),(b),(c),0,0,0)

// counted waits (T4): never drain vmcnt to 0 in steady state.
#define WAIT_VM(n)  do { asm volatile("s_waitcnt vmcnt(" #n ")" ::: "memory"); \
                         __builtin_amdgcn_sched_barrier(0); } while(0)
#define WAIT_ALL()  do { asm volatile("s_waitcnt vmcnt(0)" ::: "memory"); \
                         __builtin_amdgcn_sched_barrier(0); } while(0)
#define BARRIER()   __builtin_amdgcn_s_barrier()

__device__ __forceinline__ unsigned short f2b(float f){
  unsigned u = __float_as_uint(f);
  return (unsigned short)((u + 0x7fffu + ((u >> 16) & 1u)) >> 16);  // RNE bf16
}
__device__ __forceinline__ unsigned pk2(float a, float b){
  return (unsigned)f2b(a) | ((unsigned)f2b(b) << 16);
}
__device__ __forceinline__ float bu2f(unsigned hs){ return __uint_as_float(hs << 16); }
__device__ __forceinline__ float siluf(float x){ return x / (1.f + expf(-x)); }
__device__ __forceinline__ f32x4 zero4(){ f32x4 z; z[0]=0.f; z[1]=0.f; z[2]=0.f; z[3]=0.f; return z; }

// async global->LDS, 16B per lane. LDS dest is wave-uniform base + lane*16 (linear).
__device__ __forceinline__ void gll16(const unsigned short* g, unsigned short* l){
  __builtin_amdgcn_global_load_lds(
      (const __attribute__((address_space(1))) void*)g,
      (__attribute__((address_space(3))) void*)l, 16, 0, 0);
}

// fused 5-tensor weight convert (one launch instead of five)
#define SEGW ((size_t)NEXP*HID*DIM/4)
#define SEGS ((size_t)SHID*DIM/4)
__global__ __launch_bounds__(256) void k_cvtW(const float* __restrict__ W1, const float* __restrict__ W3,
                                              const float* __restrict__ W2, const float* __restrict__ Ws1,
                                              const float* __restrict__ Ws2,
                                              unsigned short* __restrict__ d1, unsigned short* __restrict__ d3,
                                              unsigned short* __restrict__ d2, unsigned short* __restrict__ ds1,
                                              unsigned short* __restrict__ ds2){
  size_t total = 3*SEGW + 2*SEGS;
  for (size_t i = (size_t)blockIdx.x*256 + threadIdx.x; i < total; i += (size_t)gridDim.x*256){
    const float* s; unsigned short* d; size_t off;
    if      (i <   SEGW)        { s = W1;  d = d1;  off = i; }
    else if (i < 2*SEGW)        { s = W3;  d = d3;  off = i - SEGW; }
    else if (i < 3*SEGW)        { s = W2;  d = d2;  off = i - 2*SEGW; }
    else if (i < 3*SEGW + SEGS) { s = Ws1; d = ds1; off = i - 3*SEGW; }
    else                        { s = Ws2; d = ds2; off = i - 3*SEGW - SEGS; }
    float4 v = ((const float4*)s)[off];
    uint2 q; q.x = pk2(v.x, v.y); q.y = pk2(v.z, v.w);
    ((uint2*)d)[off] = q;
  }
}

// ---------------- gate (fused with X->bf16 convert): fp32 logits, softmax, top-4 ----------------
__global__ __launch_bounds__(256) void k_gate(const float* __restrict__ X, const float* __restrict__ Wg,
                                              float* __restrict__ topw, int* __restrict__ topi,
                                              int* __restrict__ cnt, unsigned short* __restrict__ Xb){
  int lane = threadIdx.x & 63;
  int t = blockIdx.x*4 + (threadIdx.x >> 6);
  const float* xr = X + (size_t)t*DIM;
  float4 xv[8];
#pragma unroll
  for (int i=0;i<8;i++){
    xv[i] = *(const float4*)(xr + i*256 + lane*4);
    uint2 q; q.x = pk2(xv[i].x, xv[i].y); q.y = pk2(xv[i].z, xv[i].w);
    *(uint2*)(Xb + (size_t)t*DIM + i*256 + lane*4) = q;   // fused bf16 convert
  }
  float sc[NEXP];
#pragma unroll
  for (int e=0;e<NEXP;e++){
    const float* wr = Wg + e*DIM;
    float s = 0.f;
#pragma unroll
    for (int i=0;i<8;i++){
      float4 w = *(const float4*)(wr + i*256 + lane*4);
      s = fmaf(xv[i].x, w.x, s); s = fmaf(xv[i].y, w.y, s);
      s = fmaf(xv[i].z, w.z, s); s = fmaf(xv[i].w, w.w, s);
    }
#pragma unroll
    for (int d=1; d<64; d<<=1) s += __shfl_xor(s, d);
    sc[e] = s;
  }
  if (lane == 0){
    float m = sc[0];
#pragma unroll
    for (int e=1;e<NEXP;e++) m = fmaxf(m, sc[e]);
    float den = 0.f;
#pragma unroll
    for (int e=0;e<NEXP;e++){ sc[e] = expf(sc[e]-m); den += sc[e]; }
    float inv = 1.f/den;
#pragma unroll
    for (int e=0;e<NEXP;e++) sc[e] *= inv;
    for (int k=0;k<KTOP;k++){
      int bi = 0; float bv = sc[0];
#pragma unroll
      for (int e=1;e<NEXP;e++) if (sc[e] > bv){ bv = sc[e]; bi = e; }
      topw[t*KTOP+k] = bv;           // ROUTE_SCALE == 1
      topi[t*KTOP+k] = bi;
#pragma unroll
      for (int e=0;e<NEXP;e++) if (e == bi) sc[e] = -1.f;   // static-index kill
      atomicAdd(&cnt[bi], 1);
    }
  }
}

// scan + compact work-tile tables (128-row for k_g13, 256-row for k_gemm8)
__global__ void k_scan(const int* __restrict__ cnt, int* __restrict__ off, int* __restrict__ cur,
                       int* __restrict__ tab, int* __restrict__ tab2){
  if (threadIdx.x == 0){
    int a = 0;
    for (int e=0;e<NEXP;e++){ off[e] = a; cur[e] = a; a += cnt[e]; }
    int n = 0;
    for (int e=0;e<NEXP;e++){
      int nt = (cnt[e] + 127) >> 7;
      for (int r=0;r<nt;r++) tab[n++] = (e << 16) | r;
    }
    for (; n < TILEMAX; ++n) tab[n] = -1;
    n = 0;
    for (int e=0;e<NEXP;e++){
      int nt = (cnt[e] + 255) >> 8;
      for (int r=0;r<nt;r++) tab2[n++] = (e << 16) | r;
    }
    for (; n < TILEMAX2; ++n) tab2[n] = -1;
  }
}

__global__ __launch_bounds__(256) void k_place(const int* __restrict__ topi, const float* __restrict__ topw,
                                               int* __restrict__ cur, int* __restrict__ rows,
                                               float* __restrict__ rw, int* __restrict__ slotL){
  int t = blockIdx.x*256 + threadIdx.x;
#pragma unroll
  for (int k=0;k<KTOP;k++){
    int e = topi[t*KTOP+k];
    int p = atomicAdd(&cur[e], 1);
    rows[p] = t;
    rw[p]   = topw[t*KTOP+k];
    slotL[t*KTOP+k] = p;
  }
}

// fp32-weight fallback staging, BK=64 swizzled layout (8 slots/row, XOR r&7)
__device__ __forceinline__ void stage_Bf(unsigned short* lsB, const float* bF,
                                         int ldK, int bn0, int k0, int tid){
#pragma unroll
  for (int j=0;j<8;j++){
    int idx = j*256 + tid, r = idx >> 4, c4 = idx & 15;
    float4 v = *(const float4*)(bF + (size_t)(bn0 + r)*ldK + k0 + c4*4);
    uint2 q; q.x = pk2(v.x, v.y); q.y = pk2(v.z, v.w);
    *(uint2*)&lsB[r*64 + (((c4 >> 1) ^ (r & 7)) << 3) + ((c4 & 1) << 2)] = q;
  }
}

// BK=64 fragment read (8 slots/row)
__device__ __forceinline__ void read_A(bf16x8 af[4], const unsigned short* lsA, int wm, int lane, int kc){
  int s = kc*4 + (lane >> 4);
#pragma unroll
  for (int mi=0;mi<4;mi++){
    int r = wm + mi*16 + (lane & 15);
    af[mi] = *(const bf16x8*)&lsA[r*64 + ((s ^ (r & 7)) << 3)];
  }
}

// ---------------- routed up+gate proj (r6-verified 522-528us kernel, verbatim) ----------------
template<bool WBF>
__global__ __launch_bounds__(256,2) void k_g13(const unsigned short* __restrict__ Xb,
    const void* __restrict__ W1p, const void* __restrict__ W3p,
    const float* __restrict__ b1, const float* __restrict__ b3,
    const int* __restrict__ rows, const int* __restrict__ cnt, const int* __restrict__ offs,
    const int* __restrict__ tab, unsigned short* __restrict__ H1)
{
  int bid = blockIdx.x;
  int l = bid >> 3;
  int ct = l / 34;
  int slot = (bid & 7)*34 + (l - ct*34);
  int ent = tab[slot];
  if (ent < 0) return;
  int e = ent >> 16, rt = ent & 0xffff;
  int cntE = cnt[e];
  int offE = offs[e];
  int hn0 = ct*128;
  int tid = threadIdx.x, lane = tid & 63, wid = tid >> 6;
  int wm = (wid >> 1)*64, wn = (wid & 1)*64;
  __shared__ alignas(16) unsigned short lsA[8192], lsB1[8192], lsB3[8192];

  int lr8 = lane >> 3;
  int cx  = (lane & 7) ^ lr8;
  unsigned offA[4];
#pragma unroll
  for (int j=0;j<4;j++){
    int lrow = rt*128 + wid*32 + j*8 + lr8;
    int arow = rows[offE + (lrow < cntE ? lrow : cntE-1)];
    offA[j] = (unsigned)arow*DIM + (unsigned)cx*8;
  }
  unsigned offB0 = (unsigned)(hn0 + wid*32 + lr8)*DIM + (unsigned)cx*8;
  const unsigned short* b1H = (const unsigned short*)W1p + (size_t)e*HID*DIM;
  const unsigned short* b3H = (const unsigned short*)W3p + (size_t)e*HID*DIM;
  const float* b1F = (const float*)W1p + (size_t)e*HID*DIM;
  const float* b3F = (const float*)W3p + (size_t)e*HID*DIM;
  unsigned short* lA  = &lsA[wid*2048];
  unsigned short* lB1 = &lsB1[wid*2048];
  unsigned short* lB3 = &lsB3[wid*2048];

  f32x4 acc1[4][4], acc3[4][4];
#pragma unroll
  for (int i=0;i<4;i++)
#pragma unroll
    for (int j=0;j<4;j++){ acc1[i][j] = zero4(); acc3[i][j] = zero4(); }

  for (int kt=0; kt<DIM/64; ++kt){
    int k0 = kt*64;
    __syncthreads();
#pragma unroll
    for (int j=0;j<4;j++){
      gll16(Xb + offA[j] + k0, lA + j*512);
      if constexpr (WBF){
        gll16(b1H + offB0 + j*(8*DIM) + k0, lB1 + j*512);
        gll16(b3H + offB0 + j*(8*DIM) + k0, lB3 + j*512);
      }
    }
    if constexpr (!WBF){
      stage_Bf(lsB1, b1F, DIM, hn0, k0, tid);
      stage_Bf(lsB3, b3F, DIM, hn0, k0, tid);
    }
    __syncthreads();
#pragma unroll
    for (int kc=0;kc<2;kc++){
      bf16x8 af[4]; read_A(af, lsA, wm, lane, kc);
      int sB = kc*4 + (lane >> 4);
#pragma unroll
      for (int nj=0;nj<4;nj++){
        int rb = wn + nj*16 + (lane & 15);
        int lof = rb*64 + ((sB ^ (rb & 7)) << 3);
        bf16x8 bf1 = *(const bf16x8*)&lsB1[lof];
        bf16x8 bf3 = *(const bf16x8*)&lsB3[lof];
#pragma unroll
        for (int mi=0;mi<4;mi++){
          acc1[mi][nj] = MFMA16(af[mi], bf1, acc1[mi][nj]);
          acc3[mi][nj] = MFMA16(af[mi], bf3, acc3[mi][nj]);
        }
      }
    }
  }
#pragma unroll
  for (int nj=0;nj<4;nj++){
    int h = hn0 + wn + nj*16 + (lane & 15);
    float b1v = b1[e*HID + h];
    float b3v = b3[e*HID + h];
#pragma unroll
    for (int mi=0;mi<4;mi++){
#pragma unroll
      for (int r=0;r<4;r++){
        int gr = rt*128 + wm + mi*16 + (lane >> 4)*4 + r;
        if (gr < cntE){
          float u = acc1[mi][nj][r] + b1v;
          float v = acc3[mi][nj][r] + b3v;
          H1[(size_t)(offE + gr)*HID + h] = f2b(siluf(u)*v);
        }
      }
    }
  }
}

// ---------------- old generic single-B GEMM (fallback paths + gs1), 128x128x64, 2-barrier ----------------
// MODE 0=gs1(silu->Hs) 1=gs2(plain out) 2=g2 atomic 3=g2->Yrows
template<int MODE, bool WBF, int KSTEPS>
__global__ __launch_bounds__(256,2) void k_gemm(const unsigned short* __restrict__ Abase,
    const void* __restrict__ Bpv, const float* __restrict__ bias,
    float* __restrict__ outF, unsigned short* __restrict__ outH,
    const int* __restrict__ rows, const float* __restrict__ rw,
    const int* __restrict__ cnt, const int* __restrict__ offs,
    const int* __restrict__ tab)
{
  constexpr bool EXPERT = (MODE == 2 || MODE == 3);
  constexpr int KD = KSTEPS*64;
  int e = 0, ct, rt, cntE = 0, offE = 0;
  int bid = blockIdx.x;
  int l = bid >> 3;
  if constexpr (EXPERT){
    ct = l / 34;
    int slot = (bid & 7)*34 + (l - ct*34);
    int ent = tab[slot];
    if (ent < 0) return;
    e = ent >> 16; rt = ent & 0xffff;
    cntE = cnt[e];
    offE = offs[e];
  } else {
    rt = (bid & 7)*8 + (l & 7);
    ct = l >> 3;
  }
  int bn0 = ct*128, t0 = rt*128;
  int tid = threadIdx.x, lane = tid & 63, wid = tid >> 6;
  int wm = (wid >> 1)*64, wn = (wid & 1)*64;
  __shared__ alignas(16) unsigned short lsA[8192], lsB[8192];

  int lr8 = lane >> 3;
  int cx  = (lane & 7) ^ lr8;
  unsigned offA0 = 0;
  unsigned offA[4];
  if constexpr (EXPERT){
#pragma unroll
    for (int j=0;j<4;j++){
      int lrow = t0 + wid*32 + j*8 + lr8;
      int arow = offE + (lrow < cntE ? lrow : cntE-1);
      offA[j] = (unsigned)arow*KD + (unsigned)cx*8;
    }
  } else {
    offA0 = (unsigned)(t0 + wid*32 + lr8)*KD + (unsigned)cx*8;
  }
  unsigned offB0 = (unsigned)(bn0 + wid*32 + lr8)*KD + (unsigned)cx*8;
  const unsigned short* bH = (const unsigned short*)Bpv + (EXPERT ? (size_t)e*2048*KD : (size_t)0);
  const float*          bF = (const float*)Bpv          + (EXPERT ? (size_t)e*2048*KD : (size_t)0);
  const float* biasp = bias + (EXPERT ? e*DIM : 0);
  unsigned short* lA = &lsA[wid*2048];
  unsigned short* lB = &lsB[wid*2048];

  f32x4 acc[4][4];
#pragma unroll
  for (int i=0;i<4;i++)
#pragma unroll
    for (int j=0;j<4;j++) acc[i][j] = zero4();

  for (int kt=0; kt<KSTEPS; ++kt){
    int k0 = kt*64;
    __syncthreads();
#pragma unroll
    for (int j=0;j<4;j++){
      if constexpr (EXPERT) gll16(Abase + offA[j] + k0, lA + j*512);
      else                  gll16(Abase + offA0 + j*(8*KD) + k0, lA + j*512);
      if constexpr (WBF)    gll16(bH + offB0 + j*(8*KD) + k0, lB + j*512);
    }
    if constexpr (!WBF) stage_Bf(lsB, bF, KD, bn0, k0, tid);
    __syncthreads();
#pragma unroll
    for (int kc=0;kc<2;kc++){
      bf16x8 af[4]; read_A(af, lsA, wm, lane, kc);
      int sB = kc*4 + (lane >> 4);
#pragma unroll
      for (int nj=0;nj<4;nj++){
        int rb = wn + nj*16 + (lane & 15);
        bf16x8 bfr = *(const bf16x8*)&lsB[rb*64 + ((sB ^ (rb & 7)) << 3)];
#pragma unroll
        for (int mi=0;mi<4;mi++)
          acc[mi][nj] = MFMA16(af[mi], bfr, acc[mi][nj]);
      }
    }
  }
#pragma unroll
  for (int nj=0;nj<4;nj++){
    int col = bn0 + wn + nj*16 + (lane & 15);
    float bv = biasp[col];
#pragma unroll
    for (int mi=0;mi<4;mi++){
#pragma unroll
      for (int r=0;r<4;r++){
        int lr = wm + mi*16 + (lane >> 4)*4 + r;
        float v = acc[mi][nj][r] + bv;
        if constexpr (MODE == 0){
          outH[(size_t)(t0 + lr)*SHID + col] = f2b(siluf(v));
        } else if constexpr (MODE == 1){
          outF[(size_t)(t0 + lr)*DIM + col] = v;
        } else {
          int gr = t0 + lr;
          if (gr < cntE){
            int slot = offE + gr;
            float wv = rw[slot] * v;
            if constexpr (MODE == 2){
              atomicAdd(outF + (size_t)rows[slot]*DIM + col, wv);
            } else {
              outH[(size_t)slot*DIM + col] = f2b(wv);
            }
          }
        }
      }
    }
  }
}

// ================= 256x256x64 counted-vmcnt pipelined GEMM (bf16 weights only) =================
// 8 waves (2M x 4N), per-wave out 128x64 (acc[8][4]). K-tile = 8 units of 8KB (B0-3, A0-3),
// one gll16/wave per unit. 4 phases/K-tile: ph0 kc0/mi0-3, ph1 kc1/mi0-3, ph2 kc0/mi4-7,
// ph3 kc1/mi4-7. Stage kt+1 during kt: ph0->B0B1, ph1->B2B3, ph2->A0A2, ph3->A1A3.
// Waits: vmcnt(2)@ph0, vmcnt(4)@ph2 (ledger: 8 outstanding at ph0, retire the 6 consumed
// first; A1/A3 certified at ph2). 2 barriers/K-tile placed AFTER the waits.
// MODE 1=gs2(fp32 out), 3=down->Yr bf16 (A = H1, SLOT-indexed — no token gather!).
template<int MODE, int KSTEPS>
__global__ __launch_bounds__(512,1) void k_gemm8(const unsigned short* __restrict__ Abase,
    const unsigned short* __restrict__ Bb, const float* __restrict__ bias,
    float* __restrict__ outF, unsigned short* __restrict__ outH,
    const int* __restrict__ rows, const float* __restrict__ rw,
    const int* __restrict__ cnt, const int* __restrict__ offs,
    const int* __restrict__ tab2)
{
  constexpr int KD = KSTEPS*64;
  constexpr bool EXPERT = (MODE == 3);
  int bid = blockIdx.x, l = bid >> 3;
  int e = 0, ct, rt, cntE = 0, offE = 0;
  if constexpr (EXPERT){
    ct = l / 18;
    int slot = (bid & 7)*18 + (l - ct*18);
    int ent = tab2[slot];
    if (ent < 0) return;
    e = ent >> 16; rt = ent & 0xffff;
    cntE = cnt[e]; offE = offs[e];
  } else {
    rt = (bid & 7)*4 + (l & 3);
    ct = l >> 2;
  }
  int bn0 = ct*256, t0 = rt*256;
  int tid = threadIdx.x, lane = tid & 63, wid = tid >> 6;
  int wm = (wid >> 2)*128, wn = (wid & 3)*64;
  __shared__ alignas(16) unsigned short lsA[2][16384], lsB[2][16384];

  // staging: one 8KB unit (64 rows x 64 cols) per gll; lane -> row tid>>3, pre-swz chunk
  int r0 = tid >> 3;                 // [0,64)
  int cx = (tid & 7) ^ (r0 & 7);     // involution of read-side XOR
  unsigned offA[4];
#pragma unroll
  for (int u=0;u<4;u++){
    int lrow = t0 + u*64 + r0;
    int arow;
    if constexpr (EXPERT) arow = offE + (lrow < cntE ? lrow : cntE-1);  // H1 is SLOT-indexed (bugfix r13->r14)
    else                  arow = lrow;
    offA[u] = (unsigned)arow*KD + (unsigned)cx*8;
  }
  unsigned offB[4];
#pragma unroll
  for (int u=0;u<4;u++) offB[u] = (unsigned)(bn0 + u*64 + r0)*KD + (unsigned)cx*8;
  const unsigned short* Bp = Bb + (EXPERT ? (size_t)e*2048*KD : (size_t)0);
  const float* biasp = bias + (EXPERT ? e*DIM : 0);
  unsigned dst = (unsigned)tid*8;    // elems within a unit (tid*16B)

  f32x4 acc[8][4];
#pragma unroll
  for (int i=0;i<8;i++)
#pragma unroll
    for (int j=0;j<4;j++) acc[i][j] = zero4();

#define STG_A(u,b,k0)  gll16(Abase + offA[u] + (k0), &lsA[b][(u)*4096 + dst])
#define STG_B(u,b,k0)  gll16(Bp    + offB[u] + (k0), &lsB[b][(u)*4096 + dst])
#define RD8(ls,R,c)    (*(const bf16x8*)&(ls)[((R)>>6)*4096 + ((R)&63)*64 + ((((c)) ^ (((R)&63)&7)) << 3)])

  // prologue: stage K-tile 0 in consumption-certification order (oldest..newest):
  // B0 B1 B2 B3 A0 A2 | A1 A3
  STG_B(0,0,0); STG_B(1,0,0); STG_B(2,0,0); STG_B(3,0,0);
  STG_A(0,0,0); STG_A(2,0,0); STG_A(1,0,0); STG_A(3,0,0);

  bf16x8 bfr[2][4];   // [kc][nj] B fragments, held whole K-tile
  for (int kt=0; kt<KSTEPS; ++kt){
    int buf = kt & 1, nb = buf ^ 1;
    int k1 = (kt+1)*64;
    bool pf = (kt+1 < KSTEPS);
    // ---- phase 0: certify B*,A0,A2 ; stage B0,B1(next) ; compute kc0 mi0-3
    WAIT_VM(2);
    BARRIER();
    if (pf){ STG_B(0,nb,k1); STG_B(1,nb,k1); }
    {
      int c0 = 0*4 + (lane >> 4);
#pragma unroll
      for (int nj=0;nj<4;nj++) bfr[0][nj] = RD8(lsB[buf], wn + nj*16 + (lane & 15), c0);
      __builtin_amdgcn_s_setprio(1);
#pragma unroll
      for (int mi=0;mi<4;mi++){
        bf16x8 af = RD8(lsA[buf], wm + mi*16 + (lane & 15), c0);
#pragma unroll
        for (int nj=0;nj<4;nj++) acc[mi][nj] = MFMA16(af, bfr[0][nj], acc[mi][nj]);
      }
      __builtin_amdgcn_s_setprio(0);
    }
    // ---- phase 1: stage B2,B3(next) ; compute kc1 mi0-3
    if (pf){ STG_B(2,nb,k1); STG_B(3,nb,k1); }
    {
      int c1 = 1*4 + (lane >> 4);
#pragma unroll
      for (int nj=0;nj<4;nj++) bfr[1][nj] = RD8(lsB[buf], wn + nj*16 + (lane & 15), c1);
      __builtin_amdgcn_s_setprio(1);
#pragma unroll
      for (int mi=0;mi<4;mi++){
        bf16x8 af = RD8(lsA[buf], wm + mi*16 + (lane & 15), c1);
#pragma unroll
        for (int nj=0;nj<4;nj++) acc[mi][nj] = MFMA16(af, bfr[1][nj], acc[mi][nj]);
      }
      __builtin_amdgcn_s_setprio(0);
    }
    // ---- phase 2: certify A1,A3 ; stage A0,A2(next) ; compute kc0 mi4-7
    if (pf) WAIT_VM(4); else WAIT_ALL();
    BARRIER();
    if (pf){ STG_A(0,nb,k1); STG_A(2,nb,k1); }
    {
      int c0 = 0*4 + (lane >> 4);
      __builtin_amdgcn_s_setprio(1);
#pragma unroll
      for (int mi=4;mi<8;mi++){
        bf16x8 af = RD8(lsA[buf], wm + mi*16 + (lane & 15), c0);
#pragma unroll
        for (int nj=0;nj<4;nj++) acc[mi][nj] = MFMA16(af, bfr[0][nj], acc[mi][nj]);
      }
      __builtin_amdgcn_s_setprio(0);
    }
    // ---- phase 3: stage A1,A3(next) ; compute kc1 mi4-7
    if (pf){ STG_A(1,nb,k1); STG_A(3,nb,k1); }
    {
      int c1 = 1*4 + (lane >> 4);
      __builtin_amdgcn_s_setprio(1);
#pragma unroll
      for (int mi=4;mi<8;mi++){
        bf16x8 af = RD8(lsA[buf], wm + mi*16 + (lane & 15), c1);
#pragma unroll
        for (int nj=0;nj<4;nj++) acc[mi][nj] = MFMA16(af, bfr[1][nj], acc[mi][nj]);
      }
      __builtin_amdgcn_s_setprio(0);
    }
  }
#undef STG_A
#undef STG_B
#undef RD8

#pragma unroll
  for (int nj=0;nj<4;nj++){
    int col = bn0 + wn + nj*16 + (lane & 15);
    float bv = biasp[col];
#pragma unroll
    for (int mi=0;mi<8;mi++){
#pragma unroll
      for (int r=0;r<4;r++){
        int lr = wm + mi*16 + (lane >> 4)*4 + r;
        float v = acc[mi][nj][r] + bv;
        if constexpr (MODE == 1){
          outF[(size_t)(t0 + lr)*DIM + col] = v;
        } else {
          int gr = t0 + lr;
          if (gr < cntE){
            int slot = offE + gr;
            outH[(size_t)slot*DIM + col] = f2b(rw[slot] * v);
          }
        }
      }
    }
  }
}

// ---------------- deterministic combine (vectorized): out += sum_k Yrows[slot(t,k)] ----------------
__global__ __launch_bounds__(256) void k_comb(const unsigned short* __restrict__ Yr,
                                              const int* __restrict__ slotL, float* __restrict__ out){
  int i = blockIdx.x*256 + threadIdx.x;
  int t = i >> 8, c = i & 255;
  size_t ob = (size_t)t*DIM + (size_t)c*8;
  float4 a = *(float4*)(out + ob);
  float4 b = *(float4*)(out + ob + 4);
  int sl[4];
#pragma unroll
  for (int k=0;k<KTOP;k++) sl[k] = slotL[t*KTOP + k];
#pragma unroll
  for (int k=0;k<KTOP;k++){
    uint4 v = *(const uint4*)(Yr + (size_t)sl[k]*DIM + (size_t)c*8);
    a.x += bu2f(v.x & 0xffffu); a.y += bu2f(v.x >> 16);
    a.z += bu2f(v.y & 0xffffu); a.w += bu2f(v.y >> 16);
    b.x += bu2f(v.z & 0xffffu); b.y += bu2f(v.z >> 16);
    b.z += bu2f(v.w & 0xffffu); b.w += bu2f(v.w >> 16);
  }
  *(float4*)(out + ob) = a;
  *(float4*)(out + ob + 4) = b;
}

// ---------------- host ----------------
extern "C" void kernel_launch(void* const* d_in, const int* in_sizes, int n_in,
                              void* d_out, int out_size, void* d_ws, size_t ws_size,
                              hipStream_t stream)
{
  (void)in_sizes; (void)n_in; (void)out_size;
  const float* emb = (const float*)d_in[0];
  // d_in[1] (x) is shadowed in the reference; unused.
  const float* Wg  = (const float*)d_in[2];
  const float* W1  = (const float*)d_in[3];
  const float* b1  = (const float*)d_in[4];
  const float* W2  = (const float*)d_in[5];
  const float* b2  = (const float*)d_in[6];
  const float* W3  = (const float*)d_in[7];
  const float* b3  = (const float*)d_in[8];
  const float* Ws1 = (const float*)d_in[9];
  const float* bs1 = (const float*)d_in[10];
  const float* Ws2 = (const float*)d_in[11];
  const float* bs2 = (const float*)d_in[12];
  float* out = (float*)d_out;
  char* ws = (char*)d_ws;

  const size_t SZ_XB = (size_t)N_TOK*DIM*2;
  const size_t SZ_H1 = (size_t)N_TOK*KTOP*HID*2;
  const size_t SZ_HS = (size_t)N_TOK*SHID*2;
  const size_t SZ_T4 = (size_t)N_TOK*KTOP*4;
  const size_t SZ_WB = (size_t)NEXP*HID*DIM*2;
  const size_t SZ_SB = (size_t)SHID*DIM*2;
  const size_t SZ_YR = (size_t)N_TOK*KTOP*DIM*2;

  size_t off_xb = 0;
  size_t off_h1 = off_xb + SZ_XB;
  size_t off_hs = off_h1 + SZ_H1;
  size_t off_tw = off_hs + SZ_HS;
  size_t off_ti = off_tw + SZ_T4;
  size_t off_ro = off_ti + SZ_T4;
  size_t off_rw = off_ro + SZ_T4;
  size_t off_sl = off_rw + SZ_T4;
  size_t off_cnt = off_sl + SZ_T4;
  size_t off_off = off_cnt + 256;
  size_t off_cur = off_off + 256;
  size_t off_tab = off_cur + 256;
  size_t off_tab2 = off_tab + TILEMAX*4;
  size_t base_end = off_tab2 + TILEMAX2*4 + 64;
  size_t off_w1b = base_end;
  size_t off_w3b = off_w1b + SZ_WB;
  size_t off_w2b = off_w3b + SZ_WB;
  size_t off_s1b = off_w2b + SZ_WB;
  size_t off_s2b = off_s1b + SZ_SB;
  size_t wbf_end = off_s2b + SZ_SB;

  bool wbf = ws_size >= wbf_end;                 // bf16 weight cache fits?
  size_t off_yr = wbf ? wbf_end : base_end;
  bool comb = ws_size >= off_yr + SZ_YR;         // deterministic combine path fits?

  unsigned short* Xb = (unsigned short*)(ws + off_xb);
  unsigned short* H1 = (unsigned short*)(ws + off_h1);
  unsigned short* Hs = (unsigned short*)(ws + off_hs);
  float* topw = (float*)(ws + off_tw);
  int*   topi = (int*)(ws + off_ti);
  int*   rowsL= (int*)(ws + off_ro);
  float* rwL  = (float*)(ws + off_rw);
  int*   slotL= (int*)(ws + off_sl);
  int*   cntP = (int*)(ws + off_cnt);
  int*   offP = (int*)(ws + off_off);
  int*   curP = (int*)(ws + off_cur);
  int*   tabP = (int*)(ws + off_tab);
  int*   tab2P= (int*)(ws + off_tab2);
  unsigned short* Yr = (unsigned short*)(ws + off_yr);

  hipMemsetAsync(ws + off_cnt, 0, 768, stream);
  if (wbf){
    k_cvtW<<<4096, 256, 0, stream>>>(W1, W3, W2, Ws1, Ws2,
        (unsigned short*)(ws + off_w1b), (unsigned short*)(ws + off_w3b),
        (unsigned short*)(ws + off_w2b), (unsigned short*)(ws + off_s1b),
        (unsigned short*)(ws + off_s2b));
  }
  k_gate<<<2048, 256, 0, stream>>>(emb, Wg, topw, topi, cntP, Xb);  // also writes Xb (bf16)
  k_scan<<<1, 64, 0, stream>>>(cntP, offP, curP, tabP, tab2P);
  k_place<<<32, 256, 0, stream>>>(topi, topw, curP, rowsL, rwL, slotL);

  // routed up+gate: flat 2992 = 8 XCD * 11 ct * 34 slots (proven r6 kernel)
  if (wbf) k_g13<true ><<<2992, 256, 0, stream>>>(Xb, ws+off_w1b, ws+off_w3b, b1, b3, rowsL, cntP, offP, tabP, H1);
  else     k_g13<false><<<2992, 256, 0, stream>>>(Xb, W1, W3, b1, b3, rowsL, cntP, offP, tabP, H1);

  // shared up (proven 128^2 kernel): flat 1408
  if (wbf) k_gemm<0,true ,32><<<1408, 256, 0, stream>>>(Xb, ws+off_s1b, bs1, nullptr, Hs, nullptr,nullptr,nullptr,nullptr,nullptr);
  else     k_gemm<0,false,32><<<1408, 256, 0, stream>>>(Xb, Ws1, bs1, nullptr, Hs, nullptr,nullptr,nullptr,nullptr,nullptr);

  if (wbf && comb){
    // shared down, 256² pipelined: 256 blocks = exactly 1/CU; K=2816 -> 44 tiles
    k_gemm8<1,44><<<256, 512, 0, stream>>>(Hs, (unsigned short*)(ws+off_s2b), bs2, out, nullptr,
                                           nullptr, nullptr, nullptr, nullptr, nullptr);
    // routed down-proj, 256² pipelined: 1152 = 8 XCD * 8 ct * 18 slots; K=1408 -> 22 tiles
    k_gemm8<3,22><<<1152, 512, 0, stream>>>(H1, (unsigned short*)(ws+off_w2b), b2, nullptr, Yr,
                                            rowsL, rwL, cntP, offP, tab2P);
    k_comb<<<N_TOK, 256, 0, stream>>>(Yr, slotL, out);
  } else if (comb){
    k_gemm<1,false,44><<<1024, 256, 0, stream>>>(Hs, Ws2, bs2, out, nullptr, nullptr,nullptr,nullptr,nullptr,nullptr);
    k_gemm<3,false,22><<<4352, 256, 0, stream>>>(H1, W2, b2, nullptr, Yr, rowsL, rwL, cntP, offP, tabP);
    k_comb<<<N_TOK, 256, 0, stream>>>(Yr, slotL, out);
  } else {
    if (wbf) k_gemm<1,true ,44><<<1024, 256, 0, stream>>>(Hs, ws+off_s2b, bs2, out, nullptr, nullptr,nullptr,nullptr,nullptr,nullptr);
    else     k_gemm<1,false,44><<<1024, 256, 0, stream>>>(Hs, Ws2, bs2, out, nullptr, nullptr,nullptr,nullptr,nullptr,nullptr);
    if (wbf) k_gemm<2,true ,22><<<4352, 256, 0, stream>>>(H1, ws+off_w2b, b2, out, nullptr, rowsL, rwL, cntP, offP, tabP);
    else     k_gemm<2,false,22><<<4352, 256, 0, stream>>>(H1, W2, b2, out, nullptr, rowsL, rwL, cntP, offP, tabP);
  }
}

// Round 15
// 1746.285 us; speedup vs baseline: 1.1652x; 1.1652x over previous
//
#include <hip/hip_runtime.h>
#include <stdint.h>

#define N_TOK 8192
#define DIM   2048
#define NEXP  16
#define HID   1408
#define SHID  2816
#define KTOP  4
#define TILEMAX 272   // 128-row tiles: sum ceil(cnt/128) <= 256+15; 272 = 8*34

typedef __attribute__((ext_vector_type(8))) short bf16x8;
typedef __attribute__((ext_vector_type(4))) float f32x4;

#define MFMA16(a,b,c) __builtin_amdgcn_mfma_f32_16x16x32_bf16((a),(b),(c),0,0,0)

__device__ __forceinline__ unsigned short f2b(float f){
  unsigned u = __float_as_uint(f);
  return (unsigned short)((u + 0x7fffu + ((u >> 16) & 1u)) >> 16);  // RNE bf16
}
__device__ __forceinline__ unsigned pk2(float a, float b){
  return (unsigned)f2b(a) | ((unsigned)f2b(b) << 16);
}
__device__ __forceinline__ float bu2f(unsigned hs){ return __uint_as_float(hs << 16); }
__device__ __forceinline__ float siluf(float x){ return x / (1.f + expf(-x)); }
__device__ __forceinline__ f32x4 zero4(){ f32x4 z; z[0]=0.f; z[1]=0.f; z[2]=0.f; z[3]=0.f; return z; }

// async global->LDS, 16B per lane. LDS dest is wave-uniform base + lane*16 (linear).
__device__ __forceinline__ void gll16(const unsigned short* g, unsigned short* l){
  __builtin_amdgcn_global_load_lds(
      (const __attribute__((address_space(1))) void*)g,
      (__attribute__((address_space(3))) void*)l, 16, 0, 0);
}

// fused 5-tensor weight convert (one launch instead of five)
#define SEGW ((size_t)NEXP*HID*DIM/4)
#define SEGS ((size_t)SHID*DIM/4)
__global__ __launch_bounds__(256) void k_cvtW(const float* __restrict__ W1, const float* __restrict__ W3,
                                              const float* __restrict__ W2, const float* __restrict__ Ws1,
                                              const float* __restrict__ Ws2,
                                              unsigned short* __restrict__ d1, unsigned short* __restrict__ d3,
                                              unsigned short* __restrict__ d2, unsigned short* __restrict__ ds1,
                                              unsigned short* __restrict__ ds2){
  size_t total = 3*SEGW + 2*SEGS;
  for (size_t i = (size_t)blockIdx.x*256 + threadIdx.x; i < total; i += (size_t)gridDim.x*256){
    const float* s; unsigned short* d; size_t off;
    if      (i <   SEGW)        { s = W1;  d = d1;  off = i; }
    else if (i < 2*SEGW)        { s = W3;  d = d3;  off = i - SEGW; }
    else if (i < 3*SEGW)        { s = W2;  d = d2;  off = i - 2*SEGW; }
    else if (i < 3*SEGW + SEGS) { s = Ws1; d = ds1; off = i - 3*SEGW; }
    else                        { s = Ws2; d = ds2; off = i - 3*SEGW - SEGS; }
    float4 v = ((const float4*)s)[off];
    uint2 q; q.x = pk2(v.x, v.y); q.y = pk2(v.z, v.w);
    ((uint2*)d)[off] = q;
  }
}

// ---------------- gate (fused with X->bf16 convert): fp32 logits, softmax, top-4 ----------------
__global__ __launch_bounds__(256) void k_gate(const float* __restrict__ X, const float* __restrict__ Wg,
                                              float* __restrict__ topw, int* __restrict__ topi,
                                              int* __restrict__ cnt, unsigned short* __restrict__ Xb){
  int lane = threadIdx.x & 63;
  int t = blockIdx.x*4 + (threadIdx.x >> 6);
  const float* xr = X + (size_t)t*DIM;
  float4 xv[8];
#pragma unroll
  for (int i=0;i<8;i++){
    xv[i] = *(const float4*)(xr + i*256 + lane*4);
    uint2 q; q.x = pk2(xv[i].x, xv[i].y); q.y = pk2(xv[i].z, xv[i].w);
    *(uint2*)(Xb + (size_t)t*DIM + i*256 + lane*4) = q;   // fused bf16 convert
  }
  float sc[NEXP];
#pragma unroll
  for (int e=0;e<NEXP;e++){
    const float* wr = Wg + e*DIM;
    float s = 0.f;
#pragma unroll
    for (int i=0;i<8;i++){
      float4 w = *(const float4*)(wr + i*256 + lane*4);
      s = fmaf(xv[i].x, w.x, s); s = fmaf(xv[i].y, w.y, s);
      s = fmaf(xv[i].z, w.z, s); s = fmaf(xv[i].w, w.w, s);
    }
#pragma unroll
    for (int d=1; d<64; d<<=1) s += __shfl_xor(s, d);
    sc[e] = s;
  }
  if (lane == 0){
    float m = sc[0];
#pragma unroll
    for (int e=1;e<NEXP;e++) m = fmaxf(m, sc[e]);
    float den = 0.f;
#pragma unroll
    for (int e=0;e<NEXP;e++){ sc[e] = expf(sc[e]-m); den += sc[e]; }
    float inv = 1.f/den;
#pragma unroll
    for (int e=0;e<NEXP;e++) sc[e] *= inv;
    for (int k=0;k<KTOP;k++){
      int bi = 0; float bv = sc[0];
#pragma unroll
      for (int e=1;e<NEXP;e++) if (sc[e] > bv){ bv = sc[e]; bi = e; }
      topw[t*KTOP+k] = bv;           // ROUTE_SCALE == 1
      topi[t*KTOP+k] = bi;
#pragma unroll
      for (int e=0;e<NEXP;e++) if (e == bi) sc[e] = -1.f;   // static-index kill
      atomicAdd(&cnt[bi], 1);
    }
  }
}

// scan + compact work-tile table: tab[i] = (expert<<16)|row_tile, -1 padded.
__global__ void k_scan(const int* __restrict__ cnt, int* __restrict__ off, int* __restrict__ cur,
                       int* __restrict__ tab){
  if (threadIdx.x == 0){
    int a = 0;
    for (int e=0;e<NEXP;e++){ off[e] = a; cur[e] = a; a += cnt[e]; }
    int n = 0;
    for (int e=0;e<NEXP;e++){
      int nt = (cnt[e] + 127) >> 7;
      for (int r=0;r<nt;r++) tab[n++] = (e << 16) | r;
    }
    for (; n < TILEMAX; ++n) tab[n] = -1;
  }
}

__global__ __launch_bounds__(256) void k_place(const int* __restrict__ topi, const float* __restrict__ topw,
                                               int* __restrict__ cur, int* __restrict__ rows,
                                               float* __restrict__ rw, int* __restrict__ slotL){
  int t = blockIdx.x*256 + threadIdx.x;
#pragma unroll
  for (int k=0;k<KTOP;k++){
    int e = topi[t*KTOP+k];
    int p = atomicAdd(&cur[e], 1);
    rows[p] = t;
    rw[p]   = topw[t*KTOP+k];
    slotL[t*KTOP+k] = p;
  }
}

// fp32-weight fallback staging, BK=64 swizzled layout (8 slots/row, XOR r&7)
__device__ __forceinline__ void stage_Bf(unsigned short* lsB, const float* bF,
                                         int ldK, int bn0, int k0, int tid){
#pragma unroll
  for (int j=0;j<8;j++){
    int idx = j*256 + tid, r = idx >> 4, c4 = idx & 15;
    float4 v = *(const float4*)(bF + (size_t)(bn0 + r)*ldK + k0 + c4*4);
    uint2 q; q.x = pk2(v.x, v.y); q.y = pk2(v.z, v.w);
    *(uint2*)&lsB[r*64 + (((c4 >> 1) ^ (r & 7)) << 3) + ((c4 & 1) << 2)] = q;
  }
}

// BK=64 fragment read (8 slots/row)
__device__ __forceinline__ void read_A(bf16x8 af[4], const unsigned short* lsA, int wm, int lane, int kc){
  int s = kc*4 + (lane >> 4);
#pragma unroll
  for (int mi=0;mi<4;mi++){
    int r = wm + mi*16 + (lane & 15);
    af[mi] = *(const bf16x8*)&lsA[r*64 + ((s ^ (r & 7)) << 3)];
  }
}

// ---------------- routed up+gate proj (r6-verified kernel, verbatim) ----------------
// 128x128x64 tile, 4 waves, single-buffer 2-barrier. global_load_lds w=16, linear LDS,
// source k-chunk pre-XOR'd. Flat grid 2992 = 8 XCD * (11 ct * 34 slots).
template<bool WBF>
__global__ __launch_bounds__(256,2) void k_g13(const unsigned short* __restrict__ Xb,
    const void* __restrict__ W1p, const void* __restrict__ W3p,
    const float* __restrict__ b1, const float* __restrict__ b3,
    const int* __restrict__ rows, const int* __restrict__ cnt, const int* __restrict__ offs,
    const int* __restrict__ tab, unsigned short* __restrict__ H1)
{
  int bid = blockIdx.x;
  int l = bid >> 3;
  int ct = l / 34;
  int slot = (bid & 7)*34 + (l - ct*34);
  int ent = tab[slot];
  if (ent < 0) return;
  int e = ent >> 16, rt = ent & 0xffff;
  int cntE = cnt[e];
  int offE = offs[e];
  int hn0 = ct*128;
  int tid = threadIdx.x, lane = tid & 63, wid = tid >> 6;
  int wm = (wid >> 1)*64, wn = (wid & 1)*64;
  __shared__ alignas(16) unsigned short lsA[8192], lsB1[8192], lsB3[8192];

  int lr8 = lane >> 3;            // row within 8-row group
  int cx  = (lane & 7) ^ lr8;     // pre-swizzled source k-chunk (involution of read XOR)
  unsigned offA[4];
#pragma unroll
  for (int j=0;j<4;j++){
    int lrow = rt*128 + wid*32 + j*8 + lr8;   // (row & 7) == lr8
    int arow = rows[offE + (lrow < cntE ? lrow : cntE-1)];
    offA[j] = (unsigned)arow*DIM + (unsigned)cx*8;
  }
  unsigned offB0 = (unsigned)(hn0 + wid*32 + lr8)*DIM + (unsigned)cx*8;  // + j*8*DIM
  const unsigned short* b1H = (const unsigned short*)W1p + (size_t)e*HID*DIM;
  const unsigned short* b3H = (const unsigned short*)W3p + (size_t)e*HID*DIM;
  const float* b1F = (const float*)W1p + (size_t)e*HID*DIM;
  const float* b3F = (const float*)W3p + (size_t)e*HID*DIM;
  unsigned short* lA  = &lsA[wid*2048];
  unsigned short* lB1 = &lsB1[wid*2048];
  unsigned short* lB3 = &lsB3[wid*2048];

  f32x4 acc1[4][4], acc3[4][4];
#pragma unroll
  for (int i=0;i<4;i++)
#pragma unroll
    for (int j=0;j<4;j++){ acc1[i][j] = zero4(); acc3[i][j] = zero4(); }

  for (int kt=0; kt<DIM/64; ++kt){
    int k0 = kt*64;
    __syncthreads();
#pragma unroll
    for (int j=0;j<4;j++){
      gll16(Xb + offA[j] + k0, lA + j*512);
      if constexpr (WBF){
        gll16(b1H + offB0 + j*(8*DIM) + k0, lB1 + j*512);
        gll16(b3H + offB0 + j*(8*DIM) + k0, lB3 + j*512);
      }
    }
    if constexpr (!WBF){
      stage_Bf(lsB1, b1F, DIM, hn0, k0, tid);
      stage_Bf(lsB3, b3F, DIM, hn0, k0, tid);
    }
    __syncthreads();   // compiler drains vmcnt/lgkmcnt here -> staged data visible
#pragma unroll
    for (int kc=0;kc<2;kc++){
      bf16x8 af[4]; read_A(af, lsA, wm, lane, kc);
      int sB = kc*4 + (lane >> 4);
#pragma unroll
      for (int nj=0;nj<4;nj++){
        int rb = wn + nj*16 + (lane & 15);
        int lof = rb*64 + ((sB ^ (rb & 7)) << 3);
        bf16x8 bf1 = *(const bf16x8*)&lsB1[lof];
        bf16x8 bf3 = *(const bf16x8*)&lsB3[lof];
#pragma unroll
        for (int mi=0;mi<4;mi++){
          acc1[mi][nj] = MFMA16(af[mi], bf1, acc1[mi][nj]);
          acc3[mi][nj] = MFMA16(af[mi], bf3, acc3[mi][nj]);
        }
      }
    }
  }
#pragma unroll
  for (int nj=0;nj<4;nj++){
    int h = hn0 + wn + nj*16 + (lane & 15);
    float b1v = b1[e*HID + h];
    float b3v = b3[e*HID + h];
#pragma unroll
    for (int mi=0;mi<4;mi++){
#pragma unroll
      for (int r=0;r<4;r++){
        int gr = rt*128 + wm + mi*16 + (lane >> 4)*4 + r;
        if (gr < cntE){
          float u = acc1[mi][nj][r] + b1v;
          float v = acc3[mi][nj][r] + b3v;
          H1[(size_t)(offE + gr)*HID + h] = f2b(siluf(u)*v);
        }
      }
    }
  }
}

// ---------------- generic single-B GEMM (r4-verified structure), 128x128x64, 2-barrier ----------------
// MODE 0=gs1(silu->Hs) 1=gs2(plain out) 2=g2 atomic 3=g2->Yrows
// EXPERT modes (2,3): flat grid 4352 = 8 XCD * (16 ct * 34 slots), XCD-chunked.
// DENSE modes (0,1): flat grid nct*64, remapped rt=(bid&7)*8+(l&7), ct=l>>3.
template<int MODE, bool WBF, int KSTEPS>
__global__ __launch_bounds__(256,2) void k_gemm(const unsigned short* __restrict__ Abase,
    const void* __restrict__ Bpv, const float* __restrict__ bias,
    float* __restrict__ outF, unsigned short* __restrict__ outH,
    const int* __restrict__ rows, const float* __restrict__ rw,
    const int* __restrict__ cnt, const int* __restrict__ offs,
    const int* __restrict__ tab)
{
  constexpr bool EXPERT = (MODE == 2 || MODE == 3);
  constexpr int KD = KSTEPS*64;
  int e = 0, ct, rt, cntE = 0, offE = 0;
  int bid = blockIdx.x;
  int l = bid >> 3;
  if constexpr (EXPERT){
    ct = l / 34;
    int slot = (bid & 7)*34 + (l - ct*34);
    int ent = tab[slot];
    if (ent < 0) return;
    e = ent >> 16; rt = ent & 0xffff;
    cntE = cnt[e];
    offE = offs[e];
  } else {
    rt = (bid & 7)*8 + (l & 7);
    ct = l >> 3;
  }
  int bn0 = ct*128, t0 = rt*128;
  int tid = threadIdx.x, lane = tid & 63, wid = tid >> 6;
  int wm = (wid >> 1)*64, wn = (wid & 1)*64;
  __shared__ alignas(16) unsigned short lsA[8192], lsB[8192];

  int lr8 = lane >> 3;
  int cx  = (lane & 7) ^ lr8;
  unsigned offA0 = 0;
  unsigned offA[4];
  if constexpr (EXPERT){
#pragma unroll
    for (int j=0;j<4;j++){
      int lrow = t0 + wid*32 + j*8 + lr8;
      int arow = offE + (lrow < cntE ? lrow : cntE-1);
      offA[j] = (unsigned)arow*KD + (unsigned)cx*8;
    }
  } else {
    offA0 = (unsigned)(t0 + wid*32 + lr8)*KD + (unsigned)cx*8;  // + j*8*KD
  }
  unsigned offB0 = (unsigned)(bn0 + wid*32 + lr8)*KD + (unsigned)cx*8;   // + j*8*KD
  const unsigned short* bH = (const unsigned short*)Bpv + (EXPERT ? (size_t)e*2048*KD : (size_t)0);
  const float*          bF = (const float*)Bpv          + (EXPERT ? (size_t)e*2048*KD : (size_t)0);
  const float* biasp = bias + (EXPERT ? e*DIM : 0);
  unsigned short* lA = &lsA[wid*2048];
  unsigned short* lB = &lsB[wid*2048];

  f32x4 acc[4][4];
#pragma unroll
  for (int i=0;i<4;i++)
#pragma unroll
    for (int j=0;j<4;j++) acc[i][j] = zero4();

  for (int kt=0; kt<KSTEPS; ++kt){
    int k0 = kt*64;
    __syncthreads();
#pragma unroll
    for (int j=0;j<4;j++){
      if constexpr (EXPERT) gll16(Abase + offA[j] + k0, lA + j*512);
      else                  gll16(Abase + offA0 + j*(8*KD) + k0, lA + j*512);
      if constexpr (WBF)    gll16(bH + offB0 + j*(8*KD) + k0, lB + j*512);
    }
    if constexpr (!WBF) stage_Bf(lsB, bF, KD, bn0, k0, tid);
    __syncthreads();
#pragma unroll
    for (int kc=0;kc<2;kc++){
      bf16x8 af[4]; read_A(af, lsA, wm, lane, kc);
      int sB = kc*4 + (lane >> 4);
#pragma unroll
      for (int nj=0;nj<4;nj++){
        int rb = wn + nj*16 + (lane & 15);
        bf16x8 bfr = *(const bf16x8*)&lsB[rb*64 + ((sB ^ (rb & 7)) << 3)];
#pragma unroll
        for (int mi=0;mi<4;mi++)
          acc[mi][nj] = MFMA16(af[mi], bfr, acc[mi][nj]);
      }
    }
  }
#pragma unroll
  for (int nj=0;nj<4;nj++){
    int col = bn0 + wn + nj*16 + (lane & 15);
    float bv = biasp[col];
#pragma unroll
    for (int mi=0;mi<4;mi++){
#pragma unroll
      for (int r=0;r<4;r++){
        int lr = wm + mi*16 + (lane >> 4)*4 + r;
        float v = acc[mi][nj][r] + bv;
        if constexpr (MODE == 0){
          outH[(size_t)(t0 + lr)*SHID + col] = f2b(siluf(v));
        } else if constexpr (MODE == 1){
          outF[(size_t)(t0 + lr)*DIM + col] = v;
        } else {
          int gr = t0 + lr;
          if (gr < cntE){
            int slot = offE + gr;
            float wv = rw[slot] * v;
            if constexpr (MODE == 2){
              atomicAdd(outF + (size_t)rows[slot]*DIM + col, wv);
            } else {
              outH[(size_t)slot*DIM + col] = f2b(wv);
            }
          }
        }
      }
    }
  }
}

// ---------------- deterministic combine (vectorized): out += sum_k Yrows[slot(t,k)] ----------------
__global__ __launch_bounds__(256) void k_comb(const unsigned short* __restrict__ Yr,
                                              const int* __restrict__ slotL, float* __restrict__ out){
  int i = blockIdx.x*256 + threadIdx.x;
  int t = i >> 8, c = i & 255;
  size_t ob = (size_t)t*DIM + (size_t)c*8;
  float4 a = *(float4*)(out + ob);
  float4 b = *(float4*)(out + ob + 4);
  int sl[4];
#pragma unroll
  for (int k=0;k<KTOP;k++) sl[k] = slotL[t*KTOP + k];
#pragma unroll
  for (int k=0;k<KTOP;k++){
    uint4 v = *(const uint4*)(Yr + (size_t)sl[k]*DIM + (size_t)c*8);
    a.x += bu2f(v.x & 0xffffu); a.y += bu2f(v.x >> 16);
    a.z += bu2f(v.y & 0xffffu); a.w += bu2f(v.y >> 16);
    b.x += bu2f(v.z & 0xffffu); b.y += bu2f(v.z >> 16);
    b.z += bu2f(v.w & 0xffffu); b.w += bu2f(v.w >> 16);
  }
  *(float4*)(out + ob) = a;
  *(float4*)(out + ob + 4) = b;
}

// ---------------- host ----------------
extern "C" void kernel_launch(void* const* d_in, const int* in_sizes, int n_in,
                              void* d_out, int out_size, void* d_ws, size_t ws_size,
                              hipStream_t stream)
{
  (void)in_sizes; (void)n_in; (void)out_size;
  const float* emb = (const float*)d_in[0];
  // d_in[1] (x) is shadowed in the reference; unused.
  const float* Wg  = (const float*)d_in[2];
  const float* W1  = (const float*)d_in[3];
  const float* b1  = (const float*)d_in[4];
  const float* W2  = (const float*)d_in[5];
  const float* b2  = (const float*)d_in[6];
  const float* W3  = (const float*)d_in[7];
  const float* b3  = (const float*)d_in[8];
  const float* Ws1 = (const float*)d_in[9];
  const float* bs1 = (const float*)d_in[10];
  const float* Ws2 = (const float*)d_in[11];
  const float* bs2 = (const float*)d_in[12];
  float* out = (float*)d_out;
  char* ws = (char*)d_ws;

  const size_t SZ_XB = (size_t)N_TOK*DIM*2;
  const size_t SZ_H1 = (size_t)N_TOK*KTOP*HID*2;
  const size_t SZ_HS = (size_t)N_TOK*SHID*2;
  const size_t SZ_T4 = (size_t)N_TOK*KTOP*4;
  const size_t SZ_WB = (size_t)NEXP*HID*DIM*2;
  const size_t SZ_SB = (size_t)SHID*DIM*2;
  const size_t SZ_YR = (size_t)N_TOK*KTOP*DIM*2;

  size_t off_xb = 0;
  size_t off_h1 = off_xb + SZ_XB;
  size_t off_hs = off_h1 + SZ_H1;
  size_t off_tw = off_hs + SZ_HS;
  size_t off_ti = off_tw + SZ_T4;
  size_t off_ro = off_ti + SZ_T4;
  size_t off_rw = off_ro + SZ_T4;
  size_t off_sl = off_rw + SZ_T4;
  size_t off_cnt = off_sl + SZ_T4;
  size_t off_off = off_cnt + 256;
  size_t off_cur = off_off + 256;
  size_t off_tab = off_cur + 256;
  size_t base_end = off_tab + TILEMAX*4 + 64;
  size_t off_w1b = base_end;
  size_t off_w3b = off_w1b + SZ_WB;
  size_t off_w2b = off_w3b + SZ_WB;
  size_t off_s1b = off_w2b + SZ_WB;
  size_t off_s2b = off_s1b + SZ_SB;
  size_t wbf_end = off_s2b + SZ_SB;

  bool wbf = ws_size >= wbf_end;                 // bf16 weight cache fits?
  size_t off_yr = wbf ? wbf_end : base_end;
  bool comb = ws_size >= off_yr + SZ_YR;         // deterministic combine path fits?

  unsigned short* Xb = (unsigned short*)(ws + off_xb);
  unsigned short* H1 = (unsigned short*)(ws + off_h1);
  unsigned short* Hs = (unsigned short*)(ws + off_hs);
  float* topw = (float*)(ws + off_tw);
  int*   topi = (int*)(ws + off_ti);
  int*   rowsL= (int*)(ws + off_ro);
  float* rwL  = (float*)(ws + off_rw);
  int*   slotL= (int*)(ws + off_sl);
  int*   cntP = (int*)(ws + off_cnt);
  int*   offP = (int*)(ws + off_off);
  int*   curP = (int*)(ws + off_cur);
  int*   tabP = (int*)(ws + off_tab);
  unsigned short* Yr = (unsigned short*)(ws + off_yr);

  hipMemsetAsync(ws + off_cnt, 0, 768, stream);
  if (wbf){
    k_cvtW<<<4096, 256, 0, stream>>>(W1, W3, W2, Ws1, Ws2,
        (unsigned short*)(ws + off_w1b), (unsigned short*)(ws + off_w3b),
        (unsigned short*)(ws + off_w2b), (unsigned short*)(ws + off_s1b),
        (unsigned short*)(ws + off_s2b));
  }
  k_gate<<<2048, 256, 0, stream>>>(emb, Wg, topw, topi, cntP, Xb);  // also writes Xb (bf16)
  k_scan<<<1, 64, 0, stream>>>(cntP, offP, curP, tabP);
  k_place<<<32, 256, 0, stream>>>(topi, topw, curP, rowsL, rwL, slotL);

  // routed up+gate: flat 2992 = 8 XCD * 11 ct * 34 slots
  if (wbf) k_g13<true ><<<2992, 256, 0, stream>>>(Xb, ws+off_w1b, ws+off_w3b, b1, b3, rowsL, cntP, offP, tabP, H1);
  else     k_g13<false><<<2992, 256, 0, stream>>>(Xb, W1, W3, b1, b3, rowsL, cntP, offP, tabP, H1);

  // shared up: N=2816 -> 22 ct; flat 1408; K=2048
  if (wbf) k_gemm<0,true ,32><<<1408, 256, 0, stream>>>(Xb, ws+off_s1b, bs1, nullptr, Hs, nullptr,nullptr,nullptr,nullptr,nullptr);
  else     k_gemm<0,false,32><<<1408, 256, 0, stream>>>(Xb, Ws1, bs1, nullptr, Hs, nullptr,nullptr,nullptr,nullptr,nullptr);

  // shared down: N=2048 -> 16 ct; flat 1024; K=2816
  if (wbf) k_gemm<1,true ,44><<<1024, 256, 0, stream>>>(Hs, ws+off_s2b, bs2, out, nullptr, nullptr,nullptr,nullptr,nullptr,nullptr);
  else     k_gemm<1,false,44><<<1024, 256, 0, stream>>>(Hs, Ws2, bs2, out, nullptr, nullptr,nullptr,nullptr,nullptr,nullptr);

  // routed down-proj: flat 4352 = 8 XCD * 16 ct * 34 slots; K=1408
  if (comb){
    if (wbf) k_gemm<3,true ,22><<<4352, 256, 0, stream>>>(H1, ws+off_w2b, b2, nullptr, Yr, rowsL, rwL, cntP, offP, tabP);
    else     k_gemm<3,false,22><<<4352, 256, 0, stream>>>(H1, W2, b2, nullptr, Yr, rowsL, rwL, cntP, offP, tabP);
    k_comb<<<N_TOK, 256, 0, stream>>>(Yr, slotL, out);
  } else {
    if (wbf) k_gemm<2,true ,22><<<4352, 256, 0, stream>>>(H1, ws+off_w2b, b2, out, nullptr, rowsL, rwL, cntP, offP, tabP);
    else     k_gemm<2,false,22><<<4352, 256, 0, stream>>>(H1, W2, b2, out, nullptr, rowsL, rwL, cntP, offP, tabP);
  }
}